// Round 13
// baseline (1165.509 us; speedup 1.0000x reference)
//
#include <hip/hip_runtime.h>
#include <hip/hip_bf16.h>
#include <math.h>

#define B_  1024
#define S_  64
#define H_  2048
#define L_  4
#define NH_ 16
#define HD_ 128
#define WSLAB_ ((size_t)2048 * 4096)

typedef __attribute__((ext_vector_type(4))) float floatx4;
typedef __attribute__((ext_vector_type(8))) short shortx8;

__device__ __forceinline__ unsigned short f2bf(float f) {
  union { float f; unsigned int u; } v; v.f = f;
  unsigned int u = v.u;
  return (unsigned short)((u + 0x7fffu + ((u >> 16) & 1u)) >> 16);
}

__device__ __forceinline__ void gload16(const void* g, void* l) {
  __builtin_amdgcn_global_load_lds(
      (const __attribute__((address_space(1))) void*)g,
      (__attribute__((address_space(3))) void*)l, 16, 0, 0);
}

// f32 -> bf16 elementwise (8 per thread)
__global__ __launch_bounds__(256) void cvt_bf(
    const float* __restrict__ in, unsigned short* __restrict__ out, int n8)
{
  int i = blockIdx.x * 256 + threadIdx.x;
  if (i >= n8) return;
  const float4* p = (const float4*)in;
  float4 a = p[i * 2], b = p[i * 2 + 1];
  unsigned short o[8] = { f2bf(a.x), f2bf(a.y), f2bf(a.z), f2bf(a.w),
                          f2bf(b.x), f2bf(b.y), f2bf(b.z), f2bf(b.w) };
  ((uint4*)out)[i] = *(uint4*)o;
}

// transpose-convert: dst[z] bf16 [2048 n][K k] from src_z f32 [K][2048]
__global__ __launch_bounds__(256) void tconv4(
    const float* __restrict__ s0, const float* __restrict__ s1,
    const float* __restrict__ s2, const float* __restrict__ s3,
    unsigned short* __restrict__ dst, int K)
{
  const float* src = (blockIdx.z == 0) ? s0 : (blockIdx.z == 1) ? s1
                   : (blockIdx.z == 2) ? s2 : s3;
  unsigned short* out = dst + (size_t)blockIdx.z * 2048 * K;
  __shared__ float tile[64][65];
  int k0 = blockIdx.x * 64, n0 = blockIdx.y * 64;
  int t = threadIdx.x;
  int tr = t >> 4, tc = (t & 15) * 4;
  #pragma unroll
  for (int rep = 0; rep < 4; ++rep) {
    int kk = tr + rep * 16;
    float4 v = *(const float4*)(src + (size_t)(k0 + kk) * 2048 + n0 + tc);
    tile[kk][tc] = v.x; tile[kk][tc + 1] = v.y;
    tile[kk][tc + 2] = v.z; tile[kk][tc + 3] = v.w;
  }
  __syncthreads();
  int nr = t >> 2, kc = (t & 3) * 16;
  unsigned short o[16];
  #pragma unroll
  for (int j = 0; j < 16; ++j) o[j] = f2bf(tile[kc + j][nr]);
  *(uint4*)(out + (size_t)(n0 + nr) * K + k0 + kc)     = *(uint4*)&o[0];
  *(uint4*)(out + (size_t)(n0 + nr) * K + k0 + kc + 8) = *(uint4*)&o[8];
}

enum { EPI_XIN = 0, EPI_QB = 1, EPI_X2 = 2, EPI_CTX = 3 };

// 32x128-tile GEMM, K=2048, BK=64 (32 k-steps). 256 threads = 4 waves;
// wave w owns 32-col quadrant w; acc 2x2. Grid 512 = 2 blocks/CU.
template<int EPI>
__global__ __launch_bounds__(256, 2) void gemm32(
    const unsigned short* __restrict__ A0,
    const unsigned short* __restrict__ BT,
    const float* __restrict__ b0,
    const float* __restrict__ tse, const int* __restrict__ tsp,
    const float* __restrict__ res,
    float* __restrict__ Cf, unsigned short* __restrict__ Cb)
{
  const int t = threadIdx.x, wid = t >> 6, lane = t & 63, lr = lane & 15, lg = lane >> 4;
  const int g = blockIdx.x;
  const int m_base = (g >> 4) * 32;
  const int pn = g & 15;
  __shared__ unsigned short lds_a[32 * 64];    // 4 KB
  __shared__ unsigned short lds_b[128 * 64];   // 16 KB
  floatx4 acc[2][2] = {};
  const int arow = t >> 3, akc = t & 7;
  const int akcs = akc ^ (arow & 7);
  for (int kt = 0; kt < 32; ++kt) {
    {
      int gk = kt * 64 + akcs * 8;
      const unsigned short* ga;
      if (EPI == EPI_CTX) ga = A0 + ((size_t)(m_base + arow) * 16 + pn) * 2048 + gk;
      else                ga = A0 + (size_t)(m_base + arow) * 2048 + gk;
      gload16(ga, &lds_a[wid * 512]);
    }
    #pragma unroll
    for (int is = 0; is < 4; ++is) {
      int idx = is * 256 + t;
      int row = idx >> 3, kc = idx & 7;
      int kcs = kc ^ (row & 7);
      int gk = kt * 64 + kcs * 8;
      gload16(BT + (size_t)(pn * 128 + row) * 2048 + gk, &lds_b[(is * 256 + wid * 64) * 8]);
    }
    __syncthreads();
    #pragma unroll
    for (int ks = 0; ks < 2; ++ks) {
      const int cs = (((ks << 2) + lg) ^ (lr & 7)) * 8;
      shortx8 af[2], bfv[2];
      #pragma unroll
      for (int mt = 0; mt < 2; ++mt)
        af[mt] = *(shortx8*)&lds_a[(mt * 16 + lr) * 64 + cs];
      #pragma unroll
      for (int nt = 0; nt < 2; ++nt)
        bfv[nt] = *(shortx8*)&lds_b[(wid * 32 + nt * 16 + lr) * 64 + cs];
      #pragma unroll
      for (int mt = 0; mt < 2; ++mt)
        #pragma unroll
        for (int nt = 0; nt < 2; ++nt)
          acc[mt][nt] = __builtin_amdgcn_mfma_f32_16x16x32_bf16(af[mt], bfv[nt], acc[mt][nt], 0, 0, 0);
    }
    __syncthreads();
  }
  int ts = 0;
  if (EPI == EPI_XIN) ts = tsp[0];
  #pragma unroll
  for (int mt = 0; mt < 2; ++mt)
  #pragma unroll
  for (int nt = 0; nt < 2; ++nt)
  #pragma unroll
  for (int j = 0; j < 4; ++j) {
    int row = m_base + mt * 16 + lg * 4 + j;
    int col = pn * 128 + wid * 32 + nt * 16 + lr;
    size_t idx = (size_t)row * 2048 + col;
    float v = acc[mt][nt][j] + b0[col];
    if (EPI == EPI_XIN) {
      v += tse[(size_t)ts * 2048 + col];
      Cf[idx] = v; Cb[idx] = f2bf(v);
    } else if (EPI == EPI_QB) {
      Cb[idx] = f2bf(v);
    } else if (EPI == EPI_X2) {
      v += res[idx]; Cb[idx] = f2bf(v);
    } else {
      Cb[idx] = f2bf(v);
    }
  }
}

// G1': 4-panel gate dispatch, 128x128 tile, BK=64 (m97 geometry + BK64).
// z<3: gate GEMM K=4096 over A=[x|h]; z==3: cand_x K=2048 -> Cc.
// grid = 8m * 64pan = 512 (2/CU); 32 MFMA/wave between barriers.
__global__ __launch_bounds__(256, 2) void gemm_gates(
    const unsigned short* __restrict__ Ax, const unsigned short* __restrict__ Ah,
    const unsigned short* __restrict__ TW,
    const float* __restrict__ bu, const float* __restrict__ br, const float* __restrict__ bs,
    const float* __restrict__ Hf,
    float* __restrict__ U, float* __restrict__ Sg,
    unsigned short* __restrict__ rh, float* __restrict__ Cc)
{
  const int t = threadIdx.x, wid = t >> 6, lane = t & 63, lr = lane & 15, lg = lane >> 4;
  const int wr = wid >> 1, wc = wid & 1;
  const int g = blockIdx.x;
  const int m_base = (g >> 6) * 128;    // 8 m-groups
  const int pan = g & 63;
  const int n_base = (pan & 15) * 128;
  const int z = pan >> 4;
  const unsigned short* BTz = TW + (size_t)z * WSLAB_;
  __shared__ unsigned short lds_a[128 * 64];   // 16 KB
  __shared__ unsigned short lds_b[128 * 64];   // 16 KB
  floatx4 acc[4][4] = {};
  const int nkt = (z == 3) ? 32 : 64;
  for (int kt = 0; kt < nkt; ++kt) {
    #pragma unroll
    for (int is = 0; is < 4; ++is) {
      int idx = is * 256 + t;
      int row = idx >> 3, kc = idx & 7;
      int kcs = kc ^ (row & 7);
      int gk = kt * 64 + kcs * 8;
      const unsigned short* ga;
      if (z == 3 || gk < 2048) ga = Ax + (size_t)(m_base + row) * 2048 + gk;
      else                     ga = Ah + (size_t)(m_base + row) * 2048 + (gk - 2048);
      gload16(ga, &lds_a[(is * 256 + wid * 64) * 8]);
    }
    #pragma unroll
    for (int is = 0; is < 4; ++is) {
      int idx = is * 256 + t;
      int row = idx >> 3, kc = idx & 7;
      int kcs = kc ^ (row & 7);
      int gk = kt * 64 + kcs * 8;
      gload16(BTz + (size_t)(n_base + row) * 4096 + gk, &lds_b[(is * 256 + wid * 64) * 8]);
    }
    __syncthreads();
    #pragma unroll
    for (int ks = 0; ks < 2; ++ks) {
      const int cs = (((ks << 2) + lg) ^ (lr & 7)) * 8;
      shortx8 af[4], bfv[4];
      #pragma unroll
      for (int mt = 0; mt < 4; ++mt)
        af[mt] = *(shortx8*)&lds_a[(wr * 64 + mt * 16 + lr) * 64 + cs];
      #pragma unroll
      for (int nt = 0; nt < 4; ++nt)
        bfv[nt] = *(shortx8*)&lds_b[(wc * 64 + nt * 16 + lr) * 64 + cs];
      #pragma unroll
      for (int mt = 0; mt < 4; ++mt)
        #pragma unroll
        for (int nt = 0; nt < 4; ++nt)
          acc[mt][nt] = __builtin_amdgcn_mfma_f32_16x16x32_bf16(af[mt], bfv[nt], acc[mt][nt], 0, 0, 0);
    }
    __syncthreads();
  }
  #pragma unroll
  for (int mt = 0; mt < 4; ++mt)
  #pragma unroll
  for (int nt = 0; nt < 4; ++nt)
  #pragma unroll
  for (int j = 0; j < 4; ++j) {
    int row = m_base + wr * 64 + mt * 16 + lg * 4 + j;
    int col = n_base + wc * 64 + nt * 16 + lr;
    size_t idx = (size_t)row * 2048 + col;
    float v = acc[mt][nt][j];
    if (z == 0)      U[idx]  = 1.f / (1.f + expf(-(v + bu[col])));
    else if (z == 1) rh[idx] = f2bf((1.f / (1.f + expf(-(v + br[col])))) * Hf[idx]);
    else if (z == 2) Sg[idx] = 1.f / (1.f + expf(-(v + bs[col])));
    else             Cc[idx] = v;
  }
}

// G2'+tconv: blocks [0,512): cand completion, 32x128 tile BK=64 (2/CU).
// blocks [512, 8704): transpose-convert next layer's 4 gate slabs into TWnext.
__global__ __launch_bounds__(256) void cand_tconv(
    const unsigned short* __restrict__ Arh, const unsigned short* __restrict__ TW,
    const float* __restrict__ bc, const float* __restrict__ Cc,
    const float* __restrict__ U, const float* __restrict__ Sg,
    const float* __restrict__ Hf,
    float* __restrict__ nh_f, unsigned short* __restrict__ nh_b,
    const float* __restrict__ Wun, const float* __restrict__ Wrn,
    const float* __restrict__ Wsn, const float* __restrict__ Wcn,
    unsigned short* __restrict__ TWnext)
{
  __shared__ __align__(16) float smem[5120];   // 20KB arena (cand 20KB / tconv 16.6KB)
  const int t = threadIdx.x;
  if (blockIdx.x < 512) {
    unsigned short* lds_a = (unsigned short*)smem;          // 4 KB
    unsigned short* lds_b = (unsigned short*)smem + 2048;   // 16 KB @ +4KB
    const int wid = t >> 6, lane = t & 63, lr = lane & 15, lg = lane >> 4;
    const int g = blockIdx.x;
    const int m_base = (g >> 4) * 32;
    const int pn = g & 15;
    const unsigned short* BTz = TW + (size_t)3 * WSLAB_;
    floatx4 acc[2][2] = {};
    const int arow = t >> 3, akc = t & 7;
    const int akcs = akc ^ (arow & 7);
    for (int kt = 0; kt < 32; ++kt) {
      gload16(Arh + (size_t)(m_base + arow) * 2048 + kt * 64 + akcs * 8, &lds_a[wid * 512]);
      #pragma unroll
      for (int is = 0; is < 4; ++is) {
        int idx = is * 256 + t;
        int row = idx >> 3, kc = idx & 7;
        int kcs = kc ^ (row & 7);
        int gk = kt * 64 + kcs * 8;
        gload16(BTz + (size_t)(pn * 128 + row) * 4096 + 2048 + gk, &lds_b[(is * 256 + wid * 64) * 8]);
      }
      __syncthreads();
      #pragma unroll
      for (int ks = 0; ks < 2; ++ks) {
        const int cs = (((ks << 2) + lg) ^ (lr & 7)) * 8;
        shortx8 af[2], bfv[2];
        #pragma unroll
        for (int mt = 0; mt < 2; ++mt)
          af[mt] = *(shortx8*)&lds_a[(mt * 16 + lr) * 64 + cs];
        #pragma unroll
        for (int nt = 0; nt < 2; ++nt)
          bfv[nt] = *(shortx8*)&lds_b[(wid * 32 + nt * 16 + lr) * 64 + cs];
        #pragma unroll
        for (int mt = 0; mt < 2; ++mt)
          #pragma unroll
          for (int nt = 0; nt < 2; ++nt)
            acc[mt][nt] = __builtin_amdgcn_mfma_f32_16x16x32_bf16(af[mt], bfv[nt], acc[mt][nt], 0, 0, 0);
      }
      __syncthreads();
    }
    #pragma unroll
    for (int mt = 0; mt < 2; ++mt)
    #pragma unroll
    for (int nt = 0; nt < 2; ++nt)
    #pragma unroll
    for (int j = 0; j < 4; ++j) {
      int row = m_base + mt * 16 + lg * 4 + j;
      int col = pn * 128 + wid * 32 + nt * 16 + lr;
      size_t idx = (size_t)row * 2048 + col;
      float v = acc[mt][nt][j] + Cc[idx] + bc[col];
      float gl = 0.5f * v * (1.f + erff(v * 0.70710678118654752f));
      float u = U[idx], s = Sg[idx], hh = Hf[idx];
      float nh = (1.f - u) * hh + u * (s * gl + (1.f - s) * hh);
      nh_f[idx] = nh; nh_b[idx] = f2bf(nh);
    }
  } else {
    if (TWnext == nullptr) return;
    float (*tile)[65] = (float(*)[65])smem;
    int bid = blockIdx.x - 512;           // [0, 8192)
    int z = bid >> 11;
    int rem = bid & 2047;
    int k0 = (rem >> 5) * 64;
    int n0 = (rem & 31) * 64;
    const float* src = (z == 0) ? Wun : (z == 1) ? Wrn : (z == 2) ? Wsn : Wcn;
    unsigned short* outp = TWnext + (size_t)z * WSLAB_;
    int tr = t >> 4, tc = (t & 15) * 4;
    #pragma unroll
    for (int rep = 0; rep < 4; ++rep) {
      int kk = tr + rep * 16;
      float4 v = *(const float4*)(src + (size_t)(k0 + kk) * 2048 + n0 + tc);
      tile[kk][tc] = v.x; tile[kk][tc + 1] = v.y;
      tile[kk][tc + 2] = v.z; tile[kk][tc + 3] = v.w;
    }
    __syncthreads();
    int nr = t >> 2, kc = (t & 3) * 16;
    unsigned short o[16];
    #pragma unroll
    for (int j = 0; j < 16; ++j) o[j] = f2bf(tile[kc + j][nr]);
    *(uint4*)(outp + (size_t)(n0 + nr) * 4096 + k0 + kc)     = *(uint4*)&o[0];
    *(uint4*)(outp + (size_t)(n0 + nr) * 4096 + k0 + kc + 8) = *(uint4*)&o[8];
  }
}

// T[b,h,i] = sum_d q[b,h*128+d] * Wk[i,h*128+d]; 64x128 tile, K=128
__global__ __launch_bounds__(256) void gemm_t(
    const unsigned short* __restrict__ Q, const unsigned short* __restrict__ Wk,
    unsigned short* __restrict__ T)
{
  const int t = threadIdx.x, wid = t >> 6, lane = t & 63, lr = lane & 15, lg = lane >> 4;
  const int wr = wid >> 1, wc = wid & 1;
  const int h = blockIdx.z, m_base = blockIdx.x * 64, n_base = blockIdx.y * 128;
  __shared__ unsigned short lds_a[64 * 32], lds_b[128 * 32];
  floatx4 acc[2][4] = {};
  const int arow = t >> 2, akc = t & 3;
  const int akcs = akc ^ ((arow >> 1) & 3);
  for (int kt = 0; kt < 4; ++kt) {
    gload16(Q + (size_t)(m_base + arow) * 2048 + h * 128 + kt * 32 + akcs * 8,
            &lds_a[wid * 512]);
    #pragma unroll
    for (int is = 0; is < 2; ++is) {
      int idx = is * 256 + t;
      int row = idx >> 2, kc = idx & 3;
      int kcs = kc ^ ((row >> 1) & 3);
      gload16(Wk + (size_t)(n_base + row) * 2048 + h * 128 + kt * 32 + kcs * 8,
              &lds_b[(is * 256 + wid * 64) * 8]);
    }
    __syncthreads();
    const int sl = lg ^ ((lr >> 1) & 3);
    shortx8 af[2], bfv[4];
    #pragma unroll
    for (int mt = 0; mt < 2; ++mt)
      af[mt] = *(shortx8*)&lds_a[(wr * 32 + mt * 16 + lr) * 32 + sl * 8];
    #pragma unroll
    for (int nt = 0; nt < 4; ++nt)
      bfv[nt] = *(shortx8*)&lds_b[(wc * 64 + nt * 16 + lr) * 32 + sl * 8];
    #pragma unroll
    for (int mt = 0; mt < 2; ++mt)
      #pragma unroll
      for (int nt = 0; nt < 4; ++nt)
        acc[mt][nt] = __builtin_amdgcn_mfma_f32_16x16x32_bf16(af[mt], bfv[nt], acc[mt][nt], 0, 0, 0);
    __syncthreads();
  }
  #pragma unroll
  for (int mt = 0; mt < 2; ++mt)
  #pragma unroll
  for (int nt = 0; nt < 4; ++nt)
  #pragma unroll
  for (int j = 0; j < 4; ++j) {
    int row_o = m_base + wr * 32 + mt * 16 + lg * 4 + j;
    int col   = n_base + wc * 64 + nt * 16 + lr;
    T[((size_t)row_o * 16 + h) * 2048 + col] = f2bf(acc[mt][nt][j]);
  }
}

// Fused attention middle: scores (MFMA) -> softmax -> w = attn @ hist.
__global__ __launch_bounds__(256) void attn_fused(
    const unsigned short* __restrict__ T, const float* __restrict__ hist,
    unsigned short* __restrict__ Wb)
{
  const int t = threadIdx.x;
  const int wid = t >> 6, lane = t & 63, lr = lane & 15, lg = lane >> 4;
  const int b = blockIdx.x;
  __shared__ unsigned short lds_t[16 * 72];
  __shared__ unsigned short lds_h[64 * 72];
  __shared__ float sc[16 * 68];
  __shared__ float ps[64 * 16];   // [s][h] normalized attn
  floatx4 acc = {};
  for (int kt = 0; kt < 32; ++kt) {
    { int row = t >> 4, c4 = t & 15;
      int k = kt * 64 + c4 * 4;
      ushort4 v = *(const ushort4*)(T + ((size_t)b * 16 + row) * 2048 + k);
      *(ushort4*)&lds_t[row * 72 + c4 * 4] = v; }
    #pragma unroll
    for (int rep = 0; rep < 4; ++rep) {
      int idx = t + rep * 256;
      int srow = idx >> 4, c4 = idx & 15;
      int k = kt * 64 + c4 * 4;
      float4 hv = *(const float4*)(hist + ((size_t)b * 64 + srow) * 2048 + k);
      ushort4 uv; uv.x = f2bf(hv.x); uv.y = f2bf(hv.y); uv.z = f2bf(hv.z); uv.w = f2bf(hv.w);
      *(ushort4*)&lds_h[srow * 72 + c4 * 4] = uv;
    }
    __syncthreads();
    #pragma unroll
    for (int ks = 0; ks < 2; ++ks) {
      shortx8 af = *(shortx8*)&lds_t[lr * 72 + ks * 32 + lg * 8];
      shortx8 bv = *(shortx8*)&lds_h[(wid * 16 + lr) * 72 + ks * 32 + lg * 8];
      acc = __builtin_amdgcn_mfma_f32_16x16x32_bf16(af, bv, acc, 0, 0, 0);
    }
    __syncthreads();
  }
  #pragma unroll
  for (int j = 0; j < 4; ++j)
    sc[(lg * 4 + j) * 68 + wid * 16 + lr] = acc[j] * 0.088388347648318447f;
  __syncthreads();
  if (t < 64) {
    int h = t >> 2, qd = t & 3;
    float vv[16];
    float m = -1e30f;
    #pragma unroll
    for (int zz = 0; zz < 16; ++zz) { vv[zz] = sc[h * 68 + qd * 16 + zz]; m = fmaxf(m, vv[zz]); }
    m = fmaxf(m, __shfl_xor(m, 1)); m = fmaxf(m, __shfl_xor(m, 2));
    float sum = 0.f;
    #pragma unroll
    for (int zz = 0; zz < 16; ++zz) { vv[zz] = expf(vv[zz] - m); sum += vv[zz]; }
    sum += __shfl_xor(sum, 1); sum += __shfl_xor(sum, 2);
    float inv = 1.f / sum;
    #pragma unroll
    for (int zz = 0; zz < 16; ++zz)
      ps[(qd * 16 + zz) * 16 + h] = vv[zz] * inv;
  }
  __syncthreads();
  const int i0 = t * 8;
  floatx4 wacc[16][2] = {};
  const floatx4* ps4 = (const floatx4*)ps;
  for (int s = 0; s < 64; ++s) {
    const float* hp = hist + ((size_t)b * 64 + s) * 2048 + i0;
    float4 h4a = *(const float4*)hp;
    float4 h4b = *(const float4*)(hp + 4);
    floatx4 hva = { h4a.x, h4a.y, h4a.z, h4a.w };
    floatx4 hvb = { h4b.x, h4b.y, h4b.z, h4b.w };
    #pragma unroll
    for (int hq = 0; hq < 4; ++hq) {
      floatx4 p = ps4[s * 4 + hq];
      wacc[hq * 4 + 0][0] += p.x * hva; wacc[hq * 4 + 0][1] += p.x * hvb;
      wacc[hq * 4 + 1][0] += p.y * hva; wacc[hq * 4 + 1][1] += p.y * hvb;
      wacc[hq * 4 + 2][0] += p.z * hva; wacc[hq * 4 + 2][1] += p.z * hvb;
      wacc[hq * 4 + 3][0] += p.w * hva; wacc[hq * 4 + 3][1] += p.w * hvb;
    }
  }
  #pragma unroll
  for (int h = 0; h < 16; ++h) {
    unsigned short o[8];
    #pragma unroll
    for (int j = 0; j < 4; ++j) { o[j] = f2bf(wacc[h][0][j]); o[4 + j] = f2bf(wacc[h][1][j]); }
    *(uint4*)(Wb + ((size_t)b * 16 + h) * 2048 + i0) = *(uint4*)o;
  }
}

__global__ __launch_bounds__(256) void lnorm(
    const float* __restrict__ X, const float* __restrict__ gma,
    const float* __restrict__ bta, float* __restrict__ out)
{
  const int row = blockIdx.x, t = threadIdx.x;
  float4 a = *(const float4*)(X + (size_t)row * 2048 + t * 4);
  float4 c = *(const float4*)(X + (size_t)row * 2048 + 1024 + t * 4);
  float sum = a.x + a.y + a.z + a.w + c.x + c.y + c.z + c.w;
  float sq = a.x*a.x + a.y*a.y + a.z*a.z + a.w*a.w + c.x*c.x + c.y*c.y + c.z*c.z + c.w*c.w;
  #pragma unroll
  for (int off = 1; off < 64; off <<= 1) {
    sum += __shfl_xor(sum, off);
    sq  += __shfl_xor(sq, off);
  }
  __shared__ float red[8];
  int wid = t >> 6, lane = t & 63;
  if (lane == 0) { red[wid] = sum; red[wid + 4] = sq; }
  __syncthreads();
  sum = red[0] + red[1] + red[2] + red[3];
  sq  = red[4] + red[5] + red[6] + red[7];
  float mu = sum * (1.f / 2048.f);
  float var = sq * (1.f / 2048.f) - mu * mu;
  float rs = rsqrtf(var + 1e-5f);
  const float* pa = &a.x; const float* pc = &c.x;
  #pragma unroll
  for (int j = 0; j < 4; ++j) {
    int col = t * 4 + j;
    out[(size_t)row * 2048 + col] = (pa[j] - mu) * rs * gma[col] + bta[col];
  }
  #pragma unroll
  for (int j = 0; j < 4; ++j) {
    int col = 1024 + t * 4 + j;
    out[(size_t)row * 2048 + col] = (pc[j] - mu) * rs * gma[col] + bta[col];
  }
}

extern "C" void kernel_launch(void* const* d_in, const int* in_sizes, int n_in,
                              void* d_out, int out_size, void* d_ws, size_t ws_size,
                              hipStream_t stream) {
  (void)in_sizes; (void)n_in; (void)out_size; (void)ws_size;
  const float* x      = (const float*)d_in[0];
  const float* hist   = (const float*)d_in[2];
  const float* hidden = (const float*)d_in[3];
  const float* W_in   = (const float*)d_in[4];
  const float* b_in   = (const float*)d_in[5];
  const float* ts_emb = (const float*)d_in[6];
  const float* Wq     = (const float*)d_in[7];
  const float* bq     = (const float*)d_in[8];
  const float* Wk     = (const float*)d_in[9];
  const float* Wv     = (const float*)d_in[11];
  const float* bv     = (const float*)d_in[12];
  const float* Wo     = (const float*)d_in[13];
  const float* bo     = (const float*)d_in[14];
  const float* Wu     = (const float*)d_in[15];
  const float* Wr     = (const float*)d_in[16];
  const float* Wsg    = (const float*)d_in[17];
  const float* Wc     = (const float*)d_in[18];
  const float* bu     = (const float*)d_in[19];
  const float* br     = (const float*)d_in[20];
  const float* bs     = (const float*)d_in[21];
  const float* bc     = (const float*)d_in[22];
  const float* ln_g   = (const float*)d_in[23];
  const float* ln_b   = (const float*)d_in[24];
  const int*   tsp    = (const int*)d_in[25];
  float* out = (float*)d_out;

  const size_t BH = (size_t)B_ * H_;
  char* w = (char*)d_ws;
  auto take = [&](size_t bytes) { char* p = w; w += bytes; return p; };

  unsigned short* TW0  = (unsigned short*)take((size_t)4 * WSLAB_ * 2);
  unsigned short* TW1  = (unsigned short*)take((size_t)4 * WSLAB_ * 2);
  unsigned short* Tb   = (unsigned short*)take((size_t)B_ * 16 * 2048 * 2);
  unsigned short* WT4  = (unsigned short*)take((size_t)4 * H_ * H_ * 2);
  unsigned short* WinT = WT4;
  unsigned short* WqT  = WT4 + (size_t)H_ * H_;
  unsigned short* WvT  = WT4 + (size_t)2 * H_ * H_;
  unsigned short* WoT  = WT4 + (size_t)3 * H_ * H_;
  unsigned short* Wkb  = (unsigned short*)take((size_t)H_ * H_ * 2);
  unsigned short* x_bf   = (unsigned short*)take(BH * 2);
  unsigned short* h_bf   = (unsigned short*)take((size_t)L_ * BH * 2);
  unsigned short* xin_bf = (unsigned short*)take(BH * 2);
  unsigned short* q_bf   = (unsigned short*)take(BH * 2);
  unsigned short* ctx_bf = (unsigned short*)take(BH * 2);
  unsigned short* x2_bf  = (unsigned short*)take(BH * 2);
  unsigned short* rh_bf  = (unsigned short*)take(BH * 2);
  unsigned short* xa     = (unsigned short*)take(BH * 2);
  unsigned short* xb     = (unsigned short*)take(BH * 2);
  float* U   = (float*)take(BH * 4);
  float* Sg  = (float*)take(BH * 4);
  float* Cc  = (float*)take(BH * 4);
  float* XIN = out;   // f32 scratch in d_out[0:B*H]; lnorm overwrites at end

  dim3 blk(256);

  // conversions + small weight transposes + layer-0 gate transpose
  cvt_bf<<<dim3(1024), blk, 0, stream>>>(x, x_bf, (int)(BH / 8));
  cvt_bf<<<dim3(4096), blk, 0, stream>>>(hidden, h_bf, (int)(L_ * BH / 8));
  cvt_bf<<<dim3(2048), blk, 0, stream>>>(Wk, Wkb, (int)((size_t)H_ * H_ / 8));
  tconv4<<<dim3(32, 32, 4), blk, 0, stream>>>(W_in, Wq, Wv, Wo, WT4, 2048);
  tconv4<<<dim3(64, 32, 4), blk, 0, stream>>>(Wu, Wr, Wsg, Wc, TW0, 4096);

  // 1) xin = x@W_in + b_in + ts_emb[t]
  gemm32<EPI_XIN><<<dim3(512), blk, 0, stream>>>(
      x_bf, WinT, b_in, ts_emb, tsp, nullptr, XIN, xin_bf);
  // 2) q = xin@Wq + bq
  gemm32<EPI_QB><<<dim3(512), blk, 0, stream>>>(
      xin_bf, WqT, bq, nullptr, nullptr, nullptr, nullptr, q_bf);
  // 3) T = per-head Wk^T q
  gemm_t<<<dim3(16, 16, 16), blk, 0, stream>>>(q_bf, Wkb, Tb);
  // 4+5) fused scores/softmax/w (in-place on Tb)
  attn_fused<<<dim3(1024), blk, 0, stream>>>(Tb, hist, Tb);
  // 6) ctx = w @ Wv + bv
  gemm32<EPI_CTX><<<dim3(512), blk, 0, stream>>>(
      Tb, WvT, bv, nullptr, nullptr, nullptr, nullptr, ctx_bf);
  // 7) x2 = xin + ctx@Wo + bo
  gemm32<EPI_X2><<<dim3(512), blk, 0, stream>>>(
      ctx_bf, WoT, bo, nullptr, nullptr, XIN, nullptr, x2_bf);

  // 8) recurrent layers: gates (128x128 BK=64), cand (BK=64) + next-layer tconv
  unsigned short* xcur = x2_bf;
  for (int i = 0; i < L_; ++i) {
    const float* h_i = hidden + (size_t)i * BH;
    float* nh_f = out + BH + (size_t)i * BH;
    unsigned short* nh_b = (i & 1) ? xb : xa;
    unsigned short* TWcur = (i & 1) ? TW1 : TW0;
    unsigned short* TWnxt = (i < 3) ? ((i & 1) ? TW0 : TW1) : nullptr;
    gemm_gates<<<dim3(512), blk, 0, stream>>>(
        xcur, h_bf + (size_t)i * BH, TWcur,
        bu + (size_t)i * H_, br + (size_t)i * H_, bs + (size_t)i * H_,
        h_i, U, Sg, rh_bf, Cc);
    int grid = (i < 3) ? 8704 : 512;
    size_t off = (size_t)(i + 1) * WSLAB_;
    cand_tconv<<<dim3(grid), blk, 0, stream>>>(
        rh_bf, TWcur, bc + (size_t)i * H_, Cc, U, Sg, h_i, nh_f, nh_b,
        Wu + off, Wr + off, Wsg + off, Wc + off, TWnxt);
    xcur = nh_b;
  }

  // 9) layernorm of final hidden -> out[0:B*H]
  lnorm<<<dim3(1024), blk, 0, stream>>>(out + BH + (size_t)3 * BH, ln_g, ln_b, out);
}

// Round 14
// 1106.460 us; speedup vs baseline: 1.0534x; 1.0534x over previous
//
#include <hip/hip_runtime.h>
#include <hip/hip_bf16.h>
#include <math.h>

#define B_  1024
#define S_  64
#define H_  2048
#define L_  4
#define NH_ 16
#define HD_ 128
#define WSLAB_ ((size_t)2048 * 4096)

typedef __attribute__((ext_vector_type(4))) float floatx4;
typedef __attribute__((ext_vector_type(8))) short shortx8;

__device__ __forceinline__ unsigned short f2bf(float f) {
  union { float f; unsigned int u; } v; v.f = f;
  unsigned int u = v.u;
  return (unsigned short)((u + 0x7fffu + ((u >> 16) & 1u)) >> 16);
}

__device__ __forceinline__ void gload16(const void* g, void* l) {
  __builtin_amdgcn_global_load_lds(
      (const __attribute__((address_space(1))) void*)g,
      (__attribute__((address_space(3))) void*)l, 16, 0, 0);
}

// f32 -> bf16 elementwise (8 per thread)
__global__ __launch_bounds__(256) void cvt_bf(
    const float* __restrict__ in, unsigned short* __restrict__ out, int n8)
{
  int i = blockIdx.x * 256 + threadIdx.x;
  if (i >= n8) return;
  const float4* p = (const float4*)in;
  float4 a = p[i * 2], b = p[i * 2 + 1];
  unsigned short o[8] = { f2bf(a.x), f2bf(a.y), f2bf(a.z), f2bf(a.w),
                          f2bf(b.x), f2bf(b.y), f2bf(b.z), f2bf(b.w) };
  ((uint4*)out)[i] = *(uint4*)o;
}

// transpose-convert: dst[z] bf16 [2048 n][K k] from src_z f32 [K][2048]
__global__ __launch_bounds__(256) void tconv4(
    const float* __restrict__ s0, const float* __restrict__ s1,
    const float* __restrict__ s2, const float* __restrict__ s3,
    unsigned short* __restrict__ dst, int K)
{
  const float* src = (blockIdx.z == 0) ? s0 : (blockIdx.z == 1) ? s1
                   : (blockIdx.z == 2) ? s2 : s3;
  unsigned short* out = dst + (size_t)blockIdx.z * 2048 * K;
  __shared__ float tile[64][65];
  int k0 = blockIdx.x * 64, n0 = blockIdx.y * 64;
  int t = threadIdx.x;
  int tr = t >> 4, tc = (t & 15) * 4;
  #pragma unroll
  for (int rep = 0; rep < 4; ++rep) {
    int kk = tr + rep * 16;
    float4 v = *(const float4*)(src + (size_t)(k0 + kk) * 2048 + n0 + tc);
    tile[kk][tc] = v.x; tile[kk][tc + 1] = v.y;
    tile[kk][tc + 2] = v.z; tile[kk][tc + 3] = v.w;
  }
  __syncthreads();
  int nr = t >> 2, kc = (t & 3) * 16;
  unsigned short o[16];
  #pragma unroll
  for (int j = 0; j < 16; ++j) o[j] = f2bf(tile[kc + j][nr]);
  *(uint4*)(out + (size_t)(n0 + nr) * K + k0 + kc)     = *(uint4*)&o[0];
  *(uint4*)(out + (size_t)(n0 + nr) * K + k0 + kc + 8) = *(uint4*)&o[8];
}

enum { EPI_XIN = 0, EPI_QB = 1, EPI_X2 = 2, EPI_CTX = 3 };

// 32x128-tile GEMM, K=2048, BK=64 (32 k-steps). 256 threads = 4 waves;
// wave w owns 32-col quadrant w; acc 2x2. Grid 512 = 2 blocks/CU.
template<int EPI>
__global__ __launch_bounds__(256, 2) void gemm32(
    const unsigned short* __restrict__ A0,
    const unsigned short* __restrict__ BT,
    const float* __restrict__ b0,
    const float* __restrict__ tse, const int* __restrict__ tsp,
    const float* __restrict__ res,
    float* __restrict__ Cf, unsigned short* __restrict__ Cb)
{
  const int t = threadIdx.x, wid = t >> 6, lane = t & 63, lr = lane & 15, lg = lane >> 4;
  const int g = blockIdx.x;
  const int m_base = (g >> 4) * 32;
  const int pn = g & 15;
  __shared__ unsigned short lds_a[32 * 64];    // 4 KB
  __shared__ unsigned short lds_b[128 * 64];   // 16 KB
  floatx4 acc[2][2] = {};
  const int arow = t >> 3, akc = t & 7;
  const int akcs = akc ^ (arow & 7);
  for (int kt = 0; kt < 32; ++kt) {
    {
      int gk = kt * 64 + akcs * 8;
      const unsigned short* ga;
      if (EPI == EPI_CTX) ga = A0 + ((size_t)(m_base + arow) * 16 + pn) * 2048 + gk;
      else                ga = A0 + (size_t)(m_base + arow) * 2048 + gk;
      gload16(ga, &lds_a[wid * 512]);
    }
    #pragma unroll
    for (int is = 0; is < 4; ++is) {
      int idx = is * 256 + t;
      int row = idx >> 3, kc = idx & 7;
      int kcs = kc ^ (row & 7);
      int gk = kt * 64 + kcs * 8;
      gload16(BT + (size_t)(pn * 128 + row) * 2048 + gk, &lds_b[(is * 256 + wid * 64) * 8]);
    }
    __syncthreads();
    #pragma unroll
    for (int ks = 0; ks < 2; ++ks) {
      const int cs = (((ks << 2) + lg) ^ (lr & 7)) * 8;
      shortx8 af[2], bfv[2];
      #pragma unroll
      for (int mt = 0; mt < 2; ++mt)
        af[mt] = *(shortx8*)&lds_a[(mt * 16 + lr) * 64 + cs];
      #pragma unroll
      for (int nt = 0; nt < 2; ++nt)
        bfv[nt] = *(shortx8*)&lds_b[(wid * 32 + nt * 16 + lr) * 64 + cs];
      #pragma unroll
      for (int mt = 0; mt < 2; ++mt)
        #pragma unroll
        for (int nt = 0; nt < 2; ++nt)
          acc[mt][nt] = __builtin_amdgcn_mfma_f32_16x16x32_bf16(af[mt], bfv[nt], acc[mt][nt], 0, 0, 0);
    }
    __syncthreads();
  }
  int ts = 0;
  if (EPI == EPI_XIN) ts = tsp[0];
  #pragma unroll
  for (int mt = 0; mt < 2; ++mt)
  #pragma unroll
  for (int nt = 0; nt < 2; ++nt)
  #pragma unroll
  for (int j = 0; j < 4; ++j) {
    int row = m_base + mt * 16 + lg * 4 + j;
    int col = pn * 128 + wid * 32 + nt * 16 + lr;
    size_t idx = (size_t)row * 2048 + col;
    float v = acc[mt][nt][j] + b0[col];
    if (EPI == EPI_XIN) {
      v += tse[(size_t)ts * 2048 + col];
      Cf[idx] = v; Cb[idx] = f2bf(v);
    } else if (EPI == EPI_QB) {
      Cb[idx] = f2bf(v);
    } else if (EPI == EPI_X2) {
      v += res[idx]; Cb[idx] = f2bf(v);
    } else {
      Cb[idx] = f2bf(v);
    }
  }
}

// G1': 4-panel gate dispatch, BK=64. z<3: gate GEMM K=4096 over A=[x|h];
// z==3: cand_x K=2048 -> Cc. BM=64, grid 1024 (4/CU).
// NOTE: BM=128 @ 2/CU refuted twice (R7, R13) — occupancy dominates.
__global__ __launch_bounds__(256, 4) void gemm_gates(
    const unsigned short* __restrict__ Ax, const unsigned short* __restrict__ Ah,
    const unsigned short* __restrict__ TW,
    const float* __restrict__ bu, const float* __restrict__ br, const float* __restrict__ bs,
    const float* __restrict__ Hf,
    float* __restrict__ U, float* __restrict__ Sg,
    unsigned short* __restrict__ rh, float* __restrict__ Cc)
{
  const int t = threadIdx.x, wid = t >> 6, lane = t & 63, lr = lane & 15, lg = lane >> 4;
  const int wr = wid >> 1, wc = wid & 1;
  const int g = blockIdx.x;
  const int m_base = (g >> 6) * 64;     // NPAN = 64
  const int pan = g & 63;
  const int n_base = (pan & 15) * 128;
  const int z = pan >> 4;
  const unsigned short* BTz = TW + (size_t)z * WSLAB_;
  __shared__ unsigned short lds_a[64 * 64];    // 8 KB
  __shared__ unsigned short lds_b[128 * 64];   // 16 KB
  floatx4 acc[2][4] = {};
  const int nkt = (z == 3) ? 32 : 64;
  for (int kt = 0; kt < nkt; ++kt) {
    #pragma unroll
    for (int is = 0; is < 2; ++is) {
      int idx = is * 256 + t;
      int row = idx >> 3, kc = idx & 7;
      int kcs = kc ^ (row & 7);
      int gk = kt * 64 + kcs * 8;
      const unsigned short* ga;
      if (z == 3 || gk < 2048) ga = Ax + (size_t)(m_base + row) * 2048 + gk;
      else                     ga = Ah + (size_t)(m_base + row) * 2048 + (gk - 2048);
      gload16(ga, &lds_a[(is * 256 + wid * 64) * 8]);
    }
    #pragma unroll
    for (int is = 0; is < 4; ++is) {
      int idx = is * 256 + t;
      int row = idx >> 3, kc = idx & 7;
      int kcs = kc ^ (row & 7);
      int gk = kt * 64 + kcs * 8;
      gload16(BTz + (size_t)(n_base + row) * 4096 + gk, &lds_b[(is * 256 + wid * 64) * 8]);
    }
    __syncthreads();
    #pragma unroll
    for (int ks = 0; ks < 2; ++ks) {
      const int cs = (((ks << 2) + lg) ^ (lr & 7)) * 8;
      shortx8 af[2], bfv[4];
      #pragma unroll
      for (int mt = 0; mt < 2; ++mt)
        af[mt] = *(shortx8*)&lds_a[(wr * 32 + mt * 16 + lr) * 64 + cs];
      #pragma unroll
      for (int nt = 0; nt < 4; ++nt)
        bfv[nt] = *(shortx8*)&lds_b[(wc * 64 + nt * 16 + lr) * 64 + cs];
      #pragma unroll
      for (int mt = 0; mt < 2; ++mt)
        #pragma unroll
        for (int nt = 0; nt < 4; ++nt)
          acc[mt][nt] = __builtin_amdgcn_mfma_f32_16x16x32_bf16(af[mt], bfv[nt], acc[mt][nt], 0, 0, 0);
    }
    __syncthreads();
  }
  #pragma unroll
  for (int mt = 0; mt < 2; ++mt)
  #pragma unroll
  for (int nt = 0; nt < 4; ++nt)
  #pragma unroll
  for (int j = 0; j < 4; ++j) {
    int row = m_base + wr * 32 + mt * 16 + lg * 4 + j;
    int col = n_base + wc * 64 + nt * 16 + lr;
    size_t idx = (size_t)row * 2048 + col;
    float v = acc[mt][nt][j];
    if (z == 0)      U[idx]  = 1.f / (1.f + expf(-(v + bu[col])));
    else if (z == 1) rh[idx] = f2bf((1.f / (1.f + expf(-(v + br[col])))) * Hf[idx]);
    else if (z == 2) Sg[idx] = 1.f / (1.f + expf(-(v + bs[col])));
    else             Cc[idx] = v;
  }
}

// G2'+tconv: blocks [0,512): cand completion, 32x128 tile BK=64 (2/CU).
// blocks [512, 8704): transpose-convert next layer's 4 gate slabs into TWnext.
__global__ __launch_bounds__(256) void cand_tconv(
    const unsigned short* __restrict__ Arh, const unsigned short* __restrict__ TW,
    const float* __restrict__ bc, const float* __restrict__ Cc,
    const float* __restrict__ U, const float* __restrict__ Sg,
    const float* __restrict__ Hf,
    float* __restrict__ nh_f, unsigned short* __restrict__ nh_b,
    const float* __restrict__ Wun, const float* __restrict__ Wrn,
    const float* __restrict__ Wsn, const float* __restrict__ Wcn,
    unsigned short* __restrict__ TWnext)
{
  __shared__ __align__(16) float smem[5120];   // 20KB arena (cand 20KB / tconv 16.6KB)
  const int t = threadIdx.x;
  if (blockIdx.x < 512) {
    unsigned short* lds_a = (unsigned short*)smem;          // 4 KB
    unsigned short* lds_b = (unsigned short*)smem + 2048;   // 16 KB @ +4KB
    const int wid = t >> 6, lane = t & 63, lr = lane & 15, lg = lane >> 4;
    const int g = blockIdx.x;
    const int m_base = (g >> 4) * 32;
    const int pn = g & 15;
    const unsigned short* BTz = TW + (size_t)3 * WSLAB_;
    floatx4 acc[2][2] = {};
    const int arow = t >> 3, akc = t & 7;
    const int akcs = akc ^ (arow & 7);
    for (int kt = 0; kt < 32; ++kt) {
      gload16(Arh + (size_t)(m_base + arow) * 2048 + kt * 64 + akcs * 8, &lds_a[wid * 512]);
      #pragma unroll
      for (int is = 0; is < 4; ++is) {
        int idx = is * 256 + t;
        int row = idx >> 3, kc = idx & 7;
        int kcs = kc ^ (row & 7);
        int gk = kt * 64 + kcs * 8;
        gload16(BTz + (size_t)(pn * 128 + row) * 4096 + 2048 + gk, &lds_b[(is * 256 + wid * 64) * 8]);
      }
      __syncthreads();
      #pragma unroll
      for (int ks = 0; ks < 2; ++ks) {
        const int cs = (((ks << 2) + lg) ^ (lr & 7)) * 8;
        shortx8 af[2], bfv[2];
        #pragma unroll
        for (int mt = 0; mt < 2; ++mt)
          af[mt] = *(shortx8*)&lds_a[(mt * 16 + lr) * 64 + cs];
        #pragma unroll
        for (int nt = 0; nt < 2; ++nt)
          bfv[nt] = *(shortx8*)&lds_b[(wid * 32 + nt * 16 + lr) * 64 + cs];
        #pragma unroll
        for (int mt = 0; mt < 2; ++mt)
          #pragma unroll
          for (int nt = 0; nt < 2; ++nt)
            acc[mt][nt] = __builtin_amdgcn_mfma_f32_16x16x32_bf16(af[mt], bfv[nt], acc[mt][nt], 0, 0, 0);
      }
      __syncthreads();
    }
    #pragma unroll
    for (int mt = 0; mt < 2; ++mt)
    #pragma unroll
    for (int nt = 0; nt < 2; ++nt)
    #pragma unroll
    for (int j = 0; j < 4; ++j) {
      int row = m_base + mt * 16 + lg * 4 + j;
      int col = pn * 128 + wid * 32 + nt * 16 + lr;
      size_t idx = (size_t)row * 2048 + col;
      float v = acc[mt][nt][j] + Cc[idx] + bc[col];
      float gl = 0.5f * v * (1.f + erff(v * 0.70710678118654752f));
      float u = U[idx], s = Sg[idx], hh = Hf[idx];
      float nh = (1.f - u) * hh + u * (s * gl + (1.f - s) * hh);
      nh_f[idx] = nh; nh_b[idx] = f2bf(nh);
    }
  } else {
    if (TWnext == nullptr) return;
    float (*tile)[65] = (float(*)[65])smem;
    int bid = blockIdx.x - 512;           // [0, 8192)
    int z = bid >> 11;
    int rem = bid & 2047;
    int k0 = (rem >> 5) * 64;
    int n0 = (rem & 31) * 64;
    const float* src = (z == 0) ? Wun : (z == 1) ? Wrn : (z == 2) ? Wsn : Wcn;
    unsigned short* outp = TWnext + (size_t)z * WSLAB_;
    int tr = t >> 4, tc = (t & 15) * 4;
    #pragma unroll
    for (int rep = 0; rep < 4; ++rep) {
      int kk = tr + rep * 16;
      float4 v = *(const float4*)(src + (size_t)(k0 + kk) * 2048 + n0 + tc);
      tile[kk][tc] = v.x; tile[kk][tc + 1] = v.y;
      tile[kk][tc + 2] = v.z; tile[kk][tc + 3] = v.w;
    }
    __syncthreads();
    int nr = t >> 2, kc = (t & 3) * 16;
    unsigned short o[16];
    #pragma unroll
    for (int j = 0; j < 16; ++j) o[j] = f2bf(tile[kc + j][nr]);
    *(uint4*)(outp + (size_t)(n0 + nr) * 4096 + k0 + kc)     = *(uint4*)&o[0];
    *(uint4*)(outp + (size_t)(n0 + nr) * 4096 + k0 + kc + 8) = *(uint4*)&o[8];
  }
}

// T[b,h,i] = sum_d q[b,h*128+d] * Wk[i,h*128+d]; 64x128 tile, K=128
__global__ __launch_bounds__(256) void gemm_t(
    const unsigned short* __restrict__ Q, const unsigned short* __restrict__ Wk,
    unsigned short* __restrict__ T)
{
  const int t = threadIdx.x, wid = t >> 6, lane = t & 63, lr = lane & 15, lg = lane >> 4;
  const int wr = wid >> 1, wc = wid & 1;
  const int h = blockIdx.z, m_base = blockIdx.x * 64, n_base = blockIdx.y * 128;
  __shared__ unsigned short lds_a[64 * 32], lds_b[128 * 32];
  floatx4 acc[2][4] = {};
  const int arow = t >> 2, akc = t & 3;
  const int akcs = akc ^ ((arow >> 1) & 3);
  for (int kt = 0; kt < 4; ++kt) {
    gload16(Q + (size_t)(m_base + arow) * 2048 + h * 128 + kt * 32 + akcs * 8,
            &lds_a[wid * 512]);
    #pragma unroll
    for (int is = 0; is < 2; ++is) {
      int idx = is * 256 + t;
      int row = idx >> 2, kc = idx & 3;
      int kcs = kc ^ ((row >> 1) & 3);
      gload16(Wk + (size_t)(n_base + row) * 2048 + h * 128 + kt * 32 + kcs * 8,
              &lds_b[(is * 256 + wid * 64) * 8]);
    }
    __syncthreads();
    const int sl = lg ^ ((lr >> 1) & 3);
    shortx8 af[2], bfv[4];
    #pragma unroll
    for (int mt = 0; mt < 2; ++mt)
      af[mt] = *(shortx8*)&lds_a[(wr * 32 + mt * 16 + lr) * 32 + sl * 8];
    #pragma unroll
    for (int nt = 0; nt < 4; ++nt)
      bfv[nt] = *(shortx8*)&lds_b[(wc * 64 + nt * 16 + lr) * 32 + sl * 8];
    #pragma unroll
    for (int mt = 0; mt < 2; ++mt)
      #pragma unroll
      for (int nt = 0; nt < 4; ++nt)
        acc[mt][nt] = __builtin_amdgcn_mfma_f32_16x16x32_bf16(af[mt], bfv[nt], acc[mt][nt], 0, 0, 0);
    __syncthreads();
  }
  #pragma unroll
  for (int mt = 0; mt < 2; ++mt)
  #pragma unroll
  for (int nt = 0; nt < 4; ++nt)
  #pragma unroll
  for (int j = 0; j < 4; ++j) {
    int row_o = m_base + wr * 32 + mt * 16 + lg * 4 + j;
    int col   = n_base + wc * 64 + nt * 16 + lr;
    T[((size_t)row_o * 16 + h) * 2048 + col] = f2bf(acc[mt][nt][j]);
  }
}

// Fused attention middle: scores (MFMA) -> softmax -> w = attn @ hist.
__global__ __launch_bounds__(256) void attn_fused(
    const unsigned short* __restrict__ T, const float* __restrict__ hist,
    unsigned short* __restrict__ Wb)
{
  const int t = threadIdx.x;
  const int wid = t >> 6, lane = t & 63, lr = lane & 15, lg = lane >> 4;
  const int b = blockIdx.x;
  __shared__ unsigned short lds_t[16 * 72];
  __shared__ unsigned short lds_h[64 * 72];
  __shared__ float sc[16 * 68];
  __shared__ float ps[64 * 16];   // [s][h] normalized attn
  floatx4 acc = {};
  for (int kt = 0; kt < 32; ++kt) {
    { int row = t >> 4, c4 = t & 15;
      int k = kt * 64 + c4 * 4;
      ushort4 v = *(const ushort4*)(T + ((size_t)b * 16 + row) * 2048 + k);
      *(ushort4*)&lds_t[row * 72 + c4 * 4] = v; }
    #pragma unroll
    for (int rep = 0; rep < 4; ++rep) {
      int idx = t + rep * 256;
      int srow = idx >> 4, c4 = idx & 15;
      int k = kt * 64 + c4 * 4;
      float4 hv = *(const float4*)(hist + ((size_t)b * 64 + srow) * 2048 + k);
      ushort4 uv; uv.x = f2bf(hv.x); uv.y = f2bf(hv.y); uv.z = f2bf(hv.z); uv.w = f2bf(hv.w);
      *(ushort4*)&lds_h[srow * 72 + c4 * 4] = uv;
    }
    __syncthreads();
    #pragma unroll
    for (int ks = 0; ks < 2; ++ks) {
      shortx8 af = *(shortx8*)&lds_t[lr * 72 + ks * 32 + lg * 8];
      shortx8 bv = *(shortx8*)&lds_h[(wid * 16 + lr) * 72 + ks * 32 + lg * 8];
      acc = __builtin_amdgcn_mfma_f32_16x16x32_bf16(af, bv, acc, 0, 0, 0);
    }
    __syncthreads();
  }
  #pragma unroll
  for (int j = 0; j < 4; ++j)
    sc[(lg * 4 + j) * 68 + wid * 16 + lr] = acc[j] * 0.088388347648318447f;
  __syncthreads();
  if (t < 64) {
    int h = t >> 2, qd = t & 3;
    float vv[16];
    float m = -1e30f;
    #pragma unroll
    for (int zz = 0; zz < 16; ++zz) { vv[zz] = sc[h * 68 + qd * 16 + zz]; m = fmaxf(m, vv[zz]); }
    m = fmaxf(m, __shfl_xor(m, 1)); m = fmaxf(m, __shfl_xor(m, 2));
    float sum = 0.f;
    #pragma unroll
    for (int zz = 0; zz < 16; ++zz) { vv[zz] = expf(vv[zz] - m); sum += vv[zz]; }
    sum += __shfl_xor(sum, 1); sum += __shfl_xor(sum, 2);
    float inv = 1.f / sum;
    #pragma unroll
    for (int zz = 0; zz < 16; ++zz)
      ps[(qd * 16 + zz) * 16 + h] = vv[zz] * inv;
  }
  __syncthreads();
  const int i0 = t * 8;
  floatx4 wacc[16][2] = {};
  const floatx4* ps4 = (const floatx4*)ps;
  for (int s = 0; s < 64; ++s) {
    const float* hp = hist + ((size_t)b * 64 + s) * 2048 + i0;
    float4 h4a = *(const float4*)hp;
    float4 h4b = *(const float4*)(hp + 4);
    floatx4 hva = { h4a.x, h4a.y, h4a.z, h4a.w };
    floatx4 hvb = { h4b.x, h4b.y, h4b.z, h4b.w };
    #pragma unroll
    for (int hq = 0; hq < 4; ++hq) {
      floatx4 p = ps4[s * 4 + hq];
      wacc[hq * 4 + 0][0] += p.x * hva; wacc[hq * 4 + 0][1] += p.x * hvb;
      wacc[hq * 4 + 1][0] += p.y * hva; wacc[hq * 4 + 1][1] += p.y * hvb;
      wacc[hq * 4 + 2][0] += p.z * hva; wacc[hq * 4 + 2][1] += p.z * hvb;
      wacc[hq * 4 + 3][0] += p.w * hva; wacc[hq * 4 + 3][1] += p.w * hvb;
    }
  }
  #pragma unroll
  for (int h = 0; h < 16; ++h) {
    unsigned short o[8];
    #pragma unroll
    for (int j = 0; j < 4; ++j) { o[j] = f2bf(wacc[h][0][j]); o[4 + j] = f2bf(wacc[h][1][j]); }
    *(uint4*)(Wb + ((size_t)b * 16 + h) * 2048 + i0) = *(uint4*)o;
  }
}

__global__ __launch_bounds__(256) void lnorm(
    const float* __restrict__ X, const float* __restrict__ gma,
    const float* __restrict__ bta, float* __restrict__ out)
{
  const int row = blockIdx.x, t = threadIdx.x;
  float4 a = *(const float4*)(X + (size_t)row * 2048 + t * 4);
  float4 c = *(const float4*)(X + (size_t)row * 2048 + 1024 + t * 4);
  float sum = a.x + a.y + a.z + a.w + c.x + c.y + c.z + c.w;
  float sq = a.x*a.x + a.y*a.y + a.z*a.z + a.w*a.w + c.x*c.x + c.y*c.y + c.z*c.z + c.w*c.w;
  #pragma unroll
  for (int off = 1; off < 64; off <<= 1) {
    sum += __shfl_xor(sum, off);
    sq  += __shfl_xor(sq, off);
  }
  __shared__ float red[8];
  int wid = t >> 6, lane = t & 63;
  if (lane == 0) { red[wid] = sum; red[wid + 4] = sq; }
  __syncthreads();
  sum = red[0] + red[1] + red[2] + red[3];
  sq  = red[4] + red[5] + red[6] + red[7];
  float mu = sum * (1.f / 2048.f);
  float var = sq * (1.f / 2048.f) - mu * mu;
  float rs = rsqrtf(var + 1e-5f);
  const float* pa = &a.x; const float* pc = &c.x;
  #pragma unroll
  for (int j = 0; j < 4; ++j) {
    int col = t * 4 + j;
    out[(size_t)row * 2048 + col] = (pa[j] - mu) * rs * gma[col] + bta[col];
  }
  #pragma unroll
  for (int j = 0; j < 4; ++j) {
    int col = 1024 + t * 4 + j;
    out[(size_t)row * 2048 + col] = (pc[j] - mu) * rs * gma[col] + bta[col];
  }
}

extern "C" void kernel_launch(void* const* d_in, const int* in_sizes, int n_in,
                              void* d_out, int out_size, void* d_ws, size_t ws_size,
                              hipStream_t stream) {
  (void)in_sizes; (void)n_in; (void)out_size; (void)ws_size;
  const float* x      = (const float*)d_in[0];
  const float* hist   = (const float*)d_in[2];
  const float* hidden = (const float*)d_in[3];
  const float* W_in   = (const float*)d_in[4];
  const float* b_in   = (const float*)d_in[5];
  const float* ts_emb = (const float*)d_in[6];
  const float* Wq     = (const float*)d_in[7];
  const float* bq     = (const float*)d_in[8];
  const float* Wk     = (const float*)d_in[9];
  const float* Wv     = (const float*)d_in[11];
  const float* bv     = (const float*)d_in[12];
  const float* Wo     = (const float*)d_in[13];
  const float* bo     = (const float*)d_in[14];
  const float* Wu     = (const float*)d_in[15];
  const float* Wr     = (const float*)d_in[16];
  const float* Wsg    = (const float*)d_in[17];
  const float* Wc     = (const float*)d_in[18];
  const float* bu     = (const float*)d_in[19];
  const float* br     = (const float*)d_in[20];
  const float* bs     = (const float*)d_in[21];
  const float* bc     = (const float*)d_in[22];
  const float* ln_g   = (const float*)d_in[23];
  const float* ln_b   = (const float*)d_in[24];
  const int*   tsp    = (const int*)d_in[25];
  float* out = (float*)d_out;

  const size_t BH = (size_t)B_ * H_;
  char* w = (char*)d_ws;
  auto take = [&](size_t bytes) { char* p = w; w += bytes; return p; };

  unsigned short* TW0  = (unsigned short*)take((size_t)4 * WSLAB_ * 2);
  unsigned short* TW1  = (unsigned short*)take((size_t)4 * WSLAB_ * 2);
  unsigned short* Tb   = (unsigned short*)take((size_t)B_ * 16 * 2048 * 2);
  unsigned short* WT4  = (unsigned short*)take((size_t)4 * H_ * H_ * 2);
  unsigned short* WinT = WT4;
  unsigned short* WqT  = WT4 + (size_t)H_ * H_;
  unsigned short* WvT  = WT4 + (size_t)2 * H_ * H_;
  unsigned short* WoT  = WT4 + (size_t)3 * H_ * H_;
  unsigned short* Wkb  = (unsigned short*)take((size_t)H_ * H_ * 2);
  unsigned short* x_bf   = (unsigned short*)take(BH * 2);
  unsigned short* h_bf   = (unsigned short*)take((size_t)L_ * BH * 2);
  unsigned short* xin_bf = (unsigned short*)take(BH * 2);
  unsigned short* q_bf   = (unsigned short*)take(BH * 2);
  unsigned short* ctx_bf = (unsigned short*)take(BH * 2);
  unsigned short* x2_bf  = (unsigned short*)take(BH * 2);
  unsigned short* rh_bf  = (unsigned short*)take(BH * 2);
  unsigned short* xa     = (unsigned short*)take(BH * 2);
  unsigned short* xb     = (unsigned short*)take(BH * 2);
  float* U   = (float*)take(BH * 4);
  float* Sg  = (float*)take(BH * 4);
  float* Cc  = (float*)take(BH * 4);
  float* XIN = out;   // f32 scratch in d_out[0:B*H]; lnorm overwrites at end

  dim3 blk(256);

  // conversions + small weight transposes + layer-0 gate transpose
  cvt_bf<<<dim3(1024), blk, 0, stream>>>(x, x_bf, (int)(BH / 8));
  cvt_bf<<<dim3(4096), blk, 0, stream>>>(hidden, h_bf, (int)(L_ * BH / 8));
  cvt_bf<<<dim3(2048), blk, 0, stream>>>(Wk, Wkb, (int)((size_t)H_ * H_ / 8));
  tconv4<<<dim3(32, 32, 4), blk, 0, stream>>>(W_in, Wq, Wv, Wo, WT4, 2048);
  tconv4<<<dim3(64, 32, 4), blk, 0, stream>>>(Wu, Wr, Wsg, Wc, TW0, 4096);

  // 1) xin = x@W_in + b_in + ts_emb[t]
  gemm32<EPI_XIN><<<dim3(512), blk, 0, stream>>>(
      x_bf, WinT, b_in, ts_emb, tsp, nullptr, XIN, xin_bf);
  // 2) q = xin@Wq + bq
  gemm32<EPI_QB><<<dim3(512), blk, 0, stream>>>(
      xin_bf, WqT, bq, nullptr, nullptr, nullptr, nullptr, q_bf);
  // 3) T = per-head Wk^T q
  gemm_t<<<dim3(16, 16, 16), blk, 0, stream>>>(q_bf, Wkb, Tb);
  // 4+5) fused scores/softmax/w (in-place on Tb)
  attn_fused<<<dim3(1024), blk, 0, stream>>>(Tb, hist, Tb);
  // 6) ctx = w @ Wv + bv
  gemm32<EPI_CTX><<<dim3(512), blk, 0, stream>>>(
      Tb, WvT, bv, nullptr, nullptr, nullptr, nullptr, ctx_bf);
  // 7) x2 = xin + ctx@Wo + bo
  gemm32<EPI_X2><<<dim3(512), blk, 0, stream>>>(
      ctx_bf, WoT, bo, nullptr, nullptr, XIN, nullptr, x2_bf);

  // 8) recurrent layers: gates (BM=64 BK=64, 4/CU), cand (BK=64) + next-layer tconv
  unsigned short* xcur = x2_bf;
  for (int i = 0; i < L_; ++i) {
    const float* h_i = hidden + (size_t)i * BH;
    float* nh_f = out + BH + (size_t)i * BH;
    unsigned short* nh_b = (i & 1) ? xb : xa;
    unsigned short* TWcur = (i & 1) ? TW1 : TW0;
    unsigned short* TWnxt = (i < 3) ? ((i & 1) ? TW0 : TW1) : nullptr;
    gemm_gates<<<dim3(1024), blk, 0, stream>>>(
        xcur, h_bf + (size_t)i * BH, TWcur,
        bu + (size_t)i * H_, br + (size_t)i * H_, bs + (size_t)i * H_,
        h_i, U, Sg, rh_bf, Cc);
    int grid = (i < 3) ? 8704 : 512;
    size_t off = (size_t)(i + 1) * WSLAB_;
    cand_tconv<<<dim3(grid), blk, 0, stream>>>(
        rh_bf, TWcur, bc + (size_t)i * H_, Cc, U, Sg, h_i, nh_f, nh_b,
        Wu + off, Wr + off, Wsg + off, Wc + off, TWnxt);
    xcur = nh_b;
  }

  // 9) layernorm of final hidden -> out[0:B*H]
  lnorm<<<dim3(1024), blk, 0, stream>>>(out + BH + (size_t)3 * BH, ln_g, ln_b, out);
}

// Round 15
// 1088.203 us; speedup vs baseline: 1.0710x; 1.0168x over previous
//
#include <hip/hip_runtime.h>
#include <hip/hip_bf16.h>
#include <math.h>

#define B_  1024
#define S_  64
#define H_  2048
#define L_  4
#define NH_ 16
#define HD_ 128
#define WSLAB_ ((size_t)2048 * 4096)

typedef __attribute__((ext_vector_type(4))) float floatx4;
typedef __attribute__((ext_vector_type(8))) short shortx8;

__device__ __forceinline__ unsigned short f2bf(float f) {
  union { float f; unsigned int u; } v; v.f = f;
  unsigned int u = v.u;
  return (unsigned short)((u + 0x7fffu + ((u >> 16) & 1u)) >> 16);
}

__device__ __forceinline__ void gload16(const void* g, void* l) {
  __builtin_amdgcn_global_load_lds(
      (const __attribute__((address_space(1))) void*)g,
      (__attribute__((address_space(3))) void*)l, 16, 0, 0);
}

// ---- merged preamble: all independent conversions/transposes in ONE dispatch.
// blocks [0,1024):      x f32->bf16            (BH/8 vec8 units)
// blocks [1024,5120):   hidden f32->bf16       (L*BH/8)
// blocks [5120,7168):   Wk f32->bf16           (H*H/8)
// blocks [7168,11264):  tconv WT4 (W_in,Wq,Wv,Wo -> [2048][2048] B^T), K=2048
// blocks [11264,19456): tconv TW0 (Wu,Wr,Ws,Wc layer0 -> [2048][4096] B^T), K=4096
__global__ __launch_bounds__(256) void preamble(
    const float* __restrict__ x, unsigned short* __restrict__ x_bf,
    const float* __restrict__ hidden, unsigned short* __restrict__ h_bf,
    const float* __restrict__ Wk, unsigned short* __restrict__ Wkb,
    const float* __restrict__ W_in, const float* __restrict__ Wq,
    const float* __restrict__ Wv, const float* __restrict__ Wo,
    unsigned short* __restrict__ WT4,
    const float* __restrict__ Wu, const float* __restrict__ Wr,
    const float* __restrict__ Ws, const float* __restrict__ Wc,
    unsigned short* __restrict__ TW0)
{
  __shared__ __align__(16) float smem[4160];   // tconv tile [64][65]
  const int t = threadIdx.x;
  const int g = blockIdx.x;
  if (g < 7168) {
    // vectorized f32->bf16
    const float* in; unsigned short* out; int i;
    if (g < 1024)      { in = x;      out = x_bf; i = g * 256 + t; }
    else if (g < 5120) { in = hidden; out = h_bf; i = (g - 1024) * 256 + t; }
    else               { in = Wk;     out = Wkb;  i = (g - 5120) * 256 + t; }
    const float4* p = (const float4*)in;
    float4 a = p[i * 2], b = p[i * 2 + 1];
    unsigned short o[8] = { f2bf(a.x), f2bf(a.y), f2bf(a.z), f2bf(a.w),
                            f2bf(b.x), f2bf(b.y), f2bf(b.z), f2bf(b.w) };
    ((uint4*)out)[i] = *(uint4*)o;
    return;
  }
  float (*tile)[65] = (float(*)[65])smem;
  const float* src; unsigned short* outp; int K, k0, n0;
  if (g < 11264) {
    int bid = g - 7168;            // [0, 4096): z*1024 + rem
    int z = bid >> 10, rem = bid & 1023;
    k0 = (rem >> 5) * 64; n0 = (rem & 31) * 64; K = 2048;
    src = (z == 0) ? W_in : (z == 1) ? Wq : (z == 2) ? Wv : Wo;
    outp = WT4 + (size_t)z * 2048 * 2048;
  } else {
    int bid = g - 11264;           // [0, 8192): z*2048 + rem
    int z = bid >> 11, rem = bid & 2047;
    k0 = (rem >> 5) * 64; n0 = (rem & 31) * 64; K = 4096;
    src = (z == 0) ? Wu : (z == 1) ? Wr : (z == 2) ? Ws : Wc;
    outp = TW0 + (size_t)z * WSLAB_;
  }
  int tr = t >> 4, tc = (t & 15) * 4;
  #pragma unroll
  for (int rep = 0; rep < 4; ++rep) {
    int kk = tr + rep * 16;
    float4 v = *(const float4*)(src + (size_t)(k0 + kk) * 2048 + n0 + tc);
    tile[kk][tc] = v.x; tile[kk][tc + 1] = v.y;
    tile[kk][tc + 2] = v.z; tile[kk][tc + 3] = v.w;
  }
  __syncthreads();
  int nr = t >> 2, kc = (t & 3) * 16;
  unsigned short o[16];
  #pragma unroll
  for (int j = 0; j < 16; ++j) o[j] = f2bf(tile[kc + j][nr]);
  *(uint4*)(outp + (size_t)(n0 + nr) * K + k0 + kc)     = *(uint4*)&o[0];
  *(uint4*)(outp + (size_t)(n0 + nr) * K + k0 + kc + 8) = *(uint4*)&o[8];
}

enum { EPI_XIN = 0, EPI_QB = 1, EPI_X2 = 2, EPI_CTX = 3 };

// 32x128-tile GEMM, K=2048, BK=64 (32 k-steps). 256 threads = 4 waves;
// wave w owns 32-col quadrant w; acc 2x2. Grid 512 = 2 blocks/CU.
template<int EPI>
__global__ __launch_bounds__(256, 2) void gemm32(
    const unsigned short* __restrict__ A0,
    const unsigned short* __restrict__ BT,
    const float* __restrict__ b0,
    const float* __restrict__ tse, const int* __restrict__ tsp,
    const float* __restrict__ res,
    float* __restrict__ Cf, unsigned short* __restrict__ Cb)
{
  const int t = threadIdx.x, wid = t >> 6, lane = t & 63, lr = lane & 15, lg = lane >> 4;
  const int g = blockIdx.x;
  const int m_base = (g >> 4) * 32;
  const int pn = g & 15;
  __shared__ unsigned short lds_a[32 * 64];    // 4 KB
  __shared__ unsigned short lds_b[128 * 64];   // 16 KB
  floatx4 acc[2][2] = {};
  const int arow = t >> 3, akc = t & 7;
  const int akcs = akc ^ (arow & 7);
  for (int kt = 0; kt < 32; ++kt) {
    {
      int gk = kt * 64 + akcs * 8;
      const unsigned short* ga;
      if (EPI == EPI_CTX) ga = A0 + ((size_t)(m_base + arow) * 16 + pn) * 2048 + gk;
      else                ga = A0 + (size_t)(m_base + arow) * 2048 + gk;
      gload16(ga, &lds_a[wid * 512]);
    }
    #pragma unroll
    for (int is = 0; is < 4; ++is) {
      int idx = is * 256 + t;
      int row = idx >> 3, kc = idx & 7;
      int kcs = kc ^ (row & 7);
      int gk = kt * 64 + kcs * 8;
      gload16(BT + (size_t)(pn * 128 + row) * 2048 + gk, &lds_b[(is * 256 + wid * 64) * 8]);
    }
    __syncthreads();
    #pragma unroll
    for (int ks = 0; ks < 2; ++ks) {
      const int cs = (((ks << 2) + lg) ^ (lr & 7)) * 8;
      shortx8 af[2], bfv[2];
      #pragma unroll
      for (int mt = 0; mt < 2; ++mt)
        af[mt] = *(shortx8*)&lds_a[(mt * 16 + lr) * 64 + cs];
      #pragma unroll
      for (int nt = 0; nt < 2; ++nt)
        bfv[nt] = *(shortx8*)&lds_b[(wid * 32 + nt * 16 + lr) * 64 + cs];
      #pragma unroll
      for (int mt = 0; mt < 2; ++mt)
        #pragma unroll
        for (int nt = 0; nt < 2; ++nt)
          acc[mt][nt] = __builtin_amdgcn_mfma_f32_16x16x32_bf16(af[mt], bfv[nt], acc[mt][nt], 0, 0, 0);
    }
    __syncthreads();
  }
  int ts = 0;
  if (EPI == EPI_XIN) ts = tsp[0];
  #pragma unroll
  for (int mt = 0; mt < 2; ++mt)
  #pragma unroll
  for (int nt = 0; nt < 2; ++nt)
  #pragma unroll
  for (int j = 0; j < 4; ++j) {
    int row = m_base + mt * 16 + lg * 4 + j;
    int col = pn * 128 + wid * 32 + nt * 16 + lr;
    size_t idx = (size_t)row * 2048 + col;
    float v = acc[mt][nt][j] + b0[col];
    if (EPI == EPI_XIN) {
      v += tse[(size_t)ts * 2048 + col];
      Cf[idx] = v; Cb[idx] = f2bf(v);
    } else if (EPI == EPI_QB) {
      Cb[idx] = f2bf(v);
    } else if (EPI == EPI_X2) {
      v += res[idx]; Cb[idx] = f2bf(v);
    } else {
      Cb[idx] = f2bf(v);
    }
  }
}

// G1': 4-panel gate dispatch, BK=64. z<3: gate GEMM K=4096 over A=[x|h];
// z==3: cand_x K=2048 -> Cc. BM=64, grid 1024 (4/CU).
// NOTE: BM=128 @ 2/CU refuted twice (R7, R13) — occupancy dominates.
__global__ __launch_bounds__(256, 4) void gemm_gates(
    const unsigned short* __restrict__ Ax, const unsigned short* __restrict__ Ah,
    const unsigned short* __restrict__ TW,
    const float* __restrict__ bu, const float* __restrict__ br, const float* __restrict__ bs,
    const float* __restrict__ Hf,
    float* __restrict__ U, float* __restrict__ Sg,
    unsigned short* __restrict__ rh, float* __restrict__ Cc)
{
  const int t = threadIdx.x, wid = t >> 6, lane = t & 63, lr = lane & 15, lg = lane >> 4;
  const int wr = wid >> 1, wc = wid & 1;
  const int g = blockIdx.x;
  const int m_base = (g >> 6) * 64;     // NPAN = 64
  const int pan = g & 63;
  const int n_base = (pan & 15) * 128;
  const int z = pan >> 4;
  const unsigned short* BTz = TW + (size_t)z * WSLAB_;
  __shared__ unsigned short lds_a[64 * 64];    // 8 KB
  __shared__ unsigned short lds_b[128 * 64];   // 16 KB
  floatx4 acc[2][4] = {};
  const int nkt = (z == 3) ? 32 : 64;
  for (int kt = 0; kt < nkt; ++kt) {
    #pragma unroll
    for (int is = 0; is < 2; ++is) {
      int idx = is * 256 + t;
      int row = idx >> 3, kc = idx & 7;
      int kcs = kc ^ (row & 7);
      int gk = kt * 64 + kcs * 8;
      const unsigned short* ga;
      if (z == 3 || gk < 2048) ga = Ax + (size_t)(m_base + row) * 2048 + gk;
      else                     ga = Ah + (size_t)(m_base + row) * 2048 + (gk - 2048);
      gload16(ga, &lds_a[(is * 256 + wid * 64) * 8]);
    }
    #pragma unroll
    for (int is = 0; is < 4; ++is) {
      int idx = is * 256 + t;
      int row = idx >> 3, kc = idx & 7;
      int kcs = kc ^ (row & 7);
      int gk = kt * 64 + kcs * 8;
      gload16(BTz + (size_t)(n_base + row) * 4096 + gk, &lds_b[(is * 256 + wid * 64) * 8]);
    }
    __syncthreads();
    #pragma unroll
    for (int ks = 0; ks < 2; ++ks) {
      const int cs = (((ks << 2) + lg) ^ (lr & 7)) * 8;
      shortx8 af[2], bfv[4];
      #pragma unroll
      for (int mt = 0; mt < 2; ++mt)
        af[mt] = *(shortx8*)&lds_a[(wr * 32 + mt * 16 + lr) * 64 + cs];
      #pragma unroll
      for (int nt = 0; nt < 4; ++nt)
        bfv[nt] = *(shortx8*)&lds_b[(wc * 64 + nt * 16 + lr) * 64 + cs];
      #pragma unroll
      for (int mt = 0; mt < 2; ++mt)
        #pragma unroll
        for (int nt = 0; nt < 4; ++nt)
          acc[mt][nt] = __builtin_amdgcn_mfma_f32_16x16x32_bf16(af[mt], bfv[nt], acc[mt][nt], 0, 0, 0);
    }
    __syncthreads();
  }
  #pragma unroll
  for (int mt = 0; mt < 2; ++mt)
  #pragma unroll
  for (int nt = 0; nt < 4; ++nt)
  #pragma unroll
  for (int j = 0; j < 4; ++j) {
    int row = m_base + wr * 32 + mt * 16 + lg * 4 + j;
    int col = n_base + wc * 64 + nt * 16 + lr;
    size_t idx = (size_t)row * 2048 + col;
    float v = acc[mt][nt][j];
    if (z == 0)      U[idx]  = 1.f / (1.f + expf(-(v + bu[col])));
    else if (z == 1) rh[idx] = f2bf((1.f / (1.f + expf(-(v + br[col])))) * Hf[idx]);
    else if (z == 2) Sg[idx] = 1.f / (1.f + expf(-(v + bs[col])));
    else             Cc[idx] = v;
  }
}

// G2'+tconv: blocks [0,512): cand completion, 32x128 tile BK=64 (2/CU).
// blocks [512, 8704): transpose-convert next layer's 4 gate slabs into TWnext.
__global__ __launch_bounds__(256) void cand_tconv(
    const unsigned short* __restrict__ Arh, const unsigned short* __restrict__ TW,
    const float* __restrict__ bc, const float* __restrict__ Cc,
    const float* __restrict__ U, const float* __restrict__ Sg,
    const float* __restrict__ Hf,
    float* __restrict__ nh_f, unsigned short* __restrict__ nh_b,
    const float* __restrict__ Wun, const float* __restrict__ Wrn,
    const float* __restrict__ Wsn, const float* __restrict__ Wcn,
    unsigned short* __restrict__ TWnext)
{
  __shared__ __align__(16) float smem[5120];   // 20KB arena (cand 20KB / tconv 16.6KB)
  const int t = threadIdx.x;
  if (blockIdx.x < 512) {
    unsigned short* lds_a = (unsigned short*)smem;          // 4 KB
    unsigned short* lds_b = (unsigned short*)smem + 2048;   // 16 KB @ +4KB
    const int wid = t >> 6, lane = t & 63, lr = lane & 15, lg = lane >> 4;
    const int g = blockIdx.x;
    const int m_base = (g >> 4) * 32;
    const int pn = g & 15;
    const unsigned short* BTz = TW + (size_t)3 * WSLAB_;
    floatx4 acc[2][2] = {};
    const int arow = t >> 3, akc = t & 7;
    const int akcs = akc ^ (arow & 7);
    for (int kt = 0; kt < 32; ++kt) {
      gload16(Arh + (size_t)(m_base + arow) * 2048 + kt * 64 + akcs * 8, &lds_a[wid * 512]);
      #pragma unroll
      for (int is = 0; is < 4; ++is) {
        int idx = is * 256 + t;
        int row = idx >> 3, kc = idx & 7;
        int kcs = kc ^ (row & 7);
        int gk = kt * 64 + kcs * 8;
        gload16(BTz + (size_t)(pn * 128 + row) * 4096 + 2048 + gk, &lds_b[(is * 256 + wid * 64) * 8]);
      }
      __syncthreads();
      #pragma unroll
      for (int ks = 0; ks < 2; ++ks) {
        const int cs = (((ks << 2) + lg) ^ (lr & 7)) * 8;
        shortx8 af[2], bfv[2];
        #pragma unroll
        for (int mt = 0; mt < 2; ++mt)
          af[mt] = *(shortx8*)&lds_a[(mt * 16 + lr) * 64 + cs];
        #pragma unroll
        for (int nt = 0; nt < 2; ++nt)
          bfv[nt] = *(shortx8*)&lds_b[(wid * 32 + nt * 16 + lr) * 64 + cs];
        #pragma unroll
        for (int mt = 0; mt < 2; ++mt)
          #pragma unroll
          for (int nt = 0; nt < 2; ++nt)
            acc[mt][nt] = __builtin_amdgcn_mfma_f32_16x16x32_bf16(af[mt], bfv[nt], acc[mt][nt], 0, 0, 0);
      }
      __syncthreads();
    }
    #pragma unroll
    for (int mt = 0; mt < 2; ++mt)
    #pragma unroll
    for (int nt = 0; nt < 2; ++nt)
    #pragma unroll
    for (int j = 0; j < 4; ++j) {
      int row = m_base + mt * 16 + lg * 4 + j;
      int col = pn * 128 + wid * 32 + nt * 16 + lr;
      size_t idx = (size_t)row * 2048 + col;
      float v = acc[mt][nt][j] + Cc[idx] + bc[col];
      float gl = 0.5f * v * (1.f + erff(v * 0.70710678118654752f));
      float u = U[idx], s = Sg[idx], hh = Hf[idx];
      float nh = (1.f - u) * hh + u * (s * gl + (1.f - s) * hh);
      nh_f[idx] = nh; nh_b[idx] = f2bf(nh);
    }
  } else {
    if (TWnext == nullptr) return;
    float (*tile)[65] = (float(*)[65])smem;
    int bid = blockIdx.x - 512;           // [0, 8192)
    int z = bid >> 11;
    int rem = bid & 2047;
    int k0 = (rem >> 5) * 64;
    int n0 = (rem & 31) * 64;
    const float* src = (z == 0) ? Wun : (z == 1) ? Wrn : (z == 2) ? Wsn : Wcn;
    unsigned short* outp = TWnext + (size_t)z * WSLAB_;
    int tr = t >> 4, tc = (t & 15) * 4;
    #pragma unroll
    for (int rep = 0; rep < 4; ++rep) {
      int kk = tr + rep * 16;
      float4 v = *(const float4*)(src + (size_t)(k0 + kk) * 2048 + n0 + tc);
      tile[kk][tc] = v.x; tile[kk][tc + 1] = v.y;
      tile[kk][tc + 2] = v.z; tile[kk][tc + 3] = v.w;
    }
    __syncthreads();
    int nr = t >> 2, kc = (t & 3) * 16;
    unsigned short o[16];
    #pragma unroll
    for (int j = 0; j < 16; ++j) o[j] = f2bf(tile[kc + j][nr]);
    *(uint4*)(outp + (size_t)(n0 + nr) * 4096 + k0 + kc)     = *(uint4*)&o[0];
    *(uint4*)(outp + (size_t)(n0 + nr) * 4096 + k0 + kc + 8) = *(uint4*)&o[8];
  }
}

// T[b,h,i] = sum_d q[b,h*128+d] * Wk[i,h*128+d]; 64x128 tile, K=128
__global__ __launch_bounds__(256) void gemm_t(
    const unsigned short* __restrict__ Q, const unsigned short* __restrict__ Wk,
    unsigned short* __restrict__ T)
{
  const int t = threadIdx.x, wid = t >> 6, lane = t & 63, lr = lane & 15, lg = lane >> 4;
  const int wr = wid >> 1, wc = wid & 1;
  const int h = blockIdx.z, m_base = blockIdx.x * 64, n_base = blockIdx.y * 128;
  __shared__ unsigned short lds_a[64 * 32], lds_b[128 * 32];
  floatx4 acc[2][4] = {};
  const int arow = t >> 2, akc = t & 3;
  const int akcs = akc ^ ((arow >> 1) & 3);
  for (int kt = 0; kt < 4; ++kt) {
    gload16(Q + (size_t)(m_base + arow) * 2048 + h * 128 + kt * 32 + akcs * 8,
            &lds_a[wid * 512]);
    #pragma unroll
    for (int is = 0; is < 2; ++is) {
      int idx = is * 256 + t;
      int row = idx >> 2, kc = idx & 3;
      int kcs = kc ^ ((row >> 1) & 3);
      gload16(Wk + (size_t)(n_base + row) * 2048 + h * 128 + kt * 32 + kcs * 8,
              &lds_b[(is * 256 + wid * 64) * 8]);
    }
    __syncthreads();
    const int sl = lg ^ ((lr >> 1) & 3);
    shortx8 af[2], bfv[4];
    #pragma unroll
    for (int mt = 0; mt < 2; ++mt)
      af[mt] = *(shortx8*)&lds_a[(wr * 32 + mt * 16 + lr) * 32 + sl * 8];
    #pragma unroll
    for (int nt = 0; nt < 4; ++nt)
      bfv[nt] = *(shortx8*)&lds_b[(wc * 64 + nt * 16 + lr) * 32 + sl * 8];
    #pragma unroll
    for (int mt = 0; mt < 2; ++mt)
      #pragma unroll
      for (int nt = 0; nt < 4; ++nt)
        acc[mt][nt] = __builtin_amdgcn_mfma_f32_16x16x32_bf16(af[mt], bfv[nt], acc[mt][nt], 0, 0, 0);
    __syncthreads();
  }
  #pragma unroll
  for (int mt = 0; mt < 2; ++mt)
  #pragma unroll
  for (int nt = 0; nt < 4; ++nt)
  #pragma unroll
  for (int j = 0; j < 4; ++j) {
    int row_o = m_base + wr * 32 + mt * 16 + lg * 4 + j;
    int col   = n_base + wc * 64 + nt * 16 + lr;
    T[((size_t)row_o * 16 + h) * 2048 + col] = f2bf(acc[mt][nt][j]);
  }
}

// Fused attention middle: scores (MFMA) -> softmax -> w = attn @ hist.
__global__ __launch_bounds__(256) void attn_fused(
    const unsigned short* __restrict__ T, const float* __restrict__ hist,
    unsigned short* __restrict__ Wb)
{
  const int t = threadIdx.x;
  const int wid = t >> 6, lane = t & 63, lr = lane & 15, lg = lane >> 4;
  const int b = blockIdx.x;
  __shared__ unsigned short lds_t[16 * 72];
  __shared__ unsigned short lds_h[64 * 72];
  __shared__ float sc[16 * 68];
  __shared__ float ps[64 * 16];   // [s][h] normalized attn
  floatx4 acc = {};
  for (int kt = 0; kt < 32; ++kt) {
    { int row = t >> 4, c4 = t & 15;
      int k = kt * 64 + c4 * 4;
      ushort4 v = *(const ushort4*)(T + ((size_t)b * 16 + row) * 2048 + k);
      *(ushort4*)&lds_t[row * 72 + c4 * 4] = v; }
    #pragma unroll
    for (int rep = 0; rep < 4; ++rep) {
      int idx = t + rep * 256;
      int srow = idx >> 4, c4 = idx & 15;
      int k = kt * 64 + c4 * 4;
      float4 hv = *(const float4*)(hist + ((size_t)b * 64 + srow) * 2048 + k);
      ushort4 uv; uv.x = f2bf(hv.x); uv.y = f2bf(hv.y); uv.z = f2bf(hv.z); uv.w = f2bf(hv.w);
      *(ushort4*)&lds_h[srow * 72 + c4 * 4] = uv;
    }
    __syncthreads();
    #pragma unroll
    for (int ks = 0; ks < 2; ++ks) {
      shortx8 af = *(shortx8*)&lds_t[lr * 72 + ks * 32 + lg * 8];
      shortx8 bv = *(shortx8*)&lds_h[(wid * 16 + lr) * 72 + ks * 32 + lg * 8];
      acc = __builtin_amdgcn_mfma_f32_16x16x32_bf16(af, bv, acc, 0, 0, 0);
    }
    __syncthreads();
  }
  #pragma unroll
  for (int j = 0; j < 4; ++j)
    sc[(lg * 4 + j) * 68 + wid * 16 + lr] = acc[j] * 0.088388347648318447f;
  __syncthreads();
  if (t < 64) {
    int h = t >> 2, qd = t & 3;
    float vv[16];
    float m = -1e30f;
    #pragma unroll
    for (int zz = 0; zz < 16; ++zz) { vv[zz] = sc[h * 68 + qd * 16 + zz]; m = fmaxf(m, vv[zz]); }
    m = fmaxf(m, __shfl_xor(m, 1)); m = fmaxf(m, __shfl_xor(m, 2));
    float sum = 0.f;
    #pragma unroll
    for (int zz = 0; zz < 16; ++zz) { vv[zz] = expf(vv[zz] - m); sum += vv[zz]; }
    sum += __shfl_xor(sum, 1); sum += __shfl_xor(sum, 2);
    float inv = 1.f / sum;
    #pragma unroll
    for (int zz = 0; zz < 16; ++zz)
      ps[(qd * 16 + zz) * 16 + h] = vv[zz] * inv;
  }
  __syncthreads();
  const int i0 = t * 8;
  floatx4 wacc[16][2] = {};
  const floatx4* ps4 = (const floatx4*)ps;
  for (int s = 0; s < 64; ++s) {
    const float* hp = hist + ((size_t)b * 64 + s) * 2048 + i0;
    float4 h4a = *(const float4*)hp;
    float4 h4b = *(const float4*)(hp + 4);
    floatx4 hva = { h4a.x, h4a.y, h4a.z, h4a.w };
    floatx4 hvb = { h4b.x, h4b.y, h4b.z, h4b.w };
    #pragma unroll
    for (int hq = 0; hq < 4; ++hq) {
      floatx4 p = ps4[s * 4 + hq];
      wacc[hq * 4 + 0][0] += p.x * hva; wacc[hq * 4 + 0][1] += p.x * hvb;
      wacc[hq * 4 + 1][0] += p.y * hva; wacc[hq * 4 + 1][1] += p.y * hvb;
      wacc[hq * 4 + 2][0] += p.z * hva; wacc[hq * 4 + 2][1] += p.z * hvb;
      wacc[hq * 4 + 3][0] += p.w * hva; wacc[hq * 4 + 3][1] += p.w * hvb;
    }
  }
  #pragma unroll
  for (int h = 0; h < 16; ++h) {
    unsigned short o[8];
    #pragma unroll
    for (int j = 0; j < 4; ++j) { o[j] = f2bf(wacc[h][0][j]); o[4 + j] = f2bf(wacc[h][1][j]); }
    *(uint4*)(Wb + ((size_t)b * 16 + h) * 2048 + i0) = *(uint4*)o;
  }
}

__global__ __launch_bounds__(256) void lnorm(
    const float* __restrict__ X, const float* __restrict__ gma,
    const float* __restrict__ bta, float* __restrict__ out)
{
  const int row = blockIdx.x, t = threadIdx.x;
  float4 a = *(const float4*)(X + (size_t)row * 2048 + t * 4);
  float4 c = *(const float4*)(X + (size_t)row * 2048 + 1024 + t * 4);
  float sum = a.x + a.y + a.z + a.w + c.x + c.y + c.z + c.w;
  float sq = a.x*a.x + a.y*a.y + a.z*a.z + a.w*a.w + c.x*c.x + c.y*c.y + c.z*c.z + c.w*c.w;
  #pragma unroll
  for (int off = 1; off < 64; off <<= 1) {
    sum += __shfl_xor(sum, off);
    sq  += __shfl_xor(sq, off);
  }
  __shared__ float red[8];
  int wid = t >> 6, lane = t & 63;
  if (lane == 0) { red[wid] = sum; red[wid + 4] = sq; }
  __syncthreads();
  sum = red[0] + red[1] + red[2] + red[3];
  sq  = red[4] + red[5] + red[6] + red[7];
  float mu = sum * (1.f / 2048.f);
  float var = sq * (1.f / 2048.f) - mu * mu;
  float rs = rsqrtf(var + 1e-5f);
  const float* pa = &a.x; const float* pc = &c.x;
  #pragma unroll
  for (int j = 0; j < 4; ++j) {
    int col = t * 4 + j;
    out[(size_t)row * 2048 + col] = (pa[j] - mu) * rs * gma[col] + bta[col];
  }
  #pragma unroll
  for (int j = 0; j < 4; ++j) {
    int col = 1024 + t * 4 + j;
    out[(size_t)row * 2048 + col] = (pc[j] - mu) * rs * gma[col] + bta[col];
  }
}

extern "C" void kernel_launch(void* const* d_in, const int* in_sizes, int n_in,
                              void* d_out, int out_size, void* d_ws, size_t ws_size,
                              hipStream_t stream) {
  (void)in_sizes; (void)n_in; (void)out_size; (void)ws_size;
  const float* x      = (const float*)d_in[0];
  const float* hist   = (const float*)d_in[2];
  const float* hidden = (const float*)d_in[3];
  const float* W_in   = (const float*)d_in[4];
  const float* b_in   = (const float*)d_in[5];
  const float* ts_emb = (const float*)d_in[6];
  const float* Wq     = (const float*)d_in[7];
  const float* bq     = (const float*)d_in[8];
  const float* Wk     = (const float*)d_in[9];
  const float* Wv     = (const float*)d_in[11];
  const float* bv     = (const float*)d_in[12];
  const float* Wo     = (const float*)d_in[13];
  const float* bo     = (const float*)d_in[14];
  const float* Wu     = (const float*)d_in[15];
  const float* Wr     = (const float*)d_in[16];
  const float* Wsg    = (const float*)d_in[17];
  const float* Wc     = (const float*)d_in[18];
  const float* bu     = (const float*)d_in[19];
  const float* br     = (const float*)d_in[20];
  const float* bs     = (const float*)d_in[21];
  const float* bc     = (const float*)d_in[22];
  const float* ln_g   = (const float*)d_in[23];
  const float* ln_b   = (const float*)d_in[24];
  const int*   tsp    = (const int*)d_in[25];
  float* out = (float*)d_out;

  const size_t BH = (size_t)B_ * H_;
  char* w = (char*)d_ws;
  auto take = [&](size_t bytes) { char* p = w; w += bytes; return p; };

  unsigned short* TW0  = (unsigned short*)take((size_t)4 * WSLAB_ * 2);
  unsigned short* TW1  = (unsigned short*)take((size_t)4 * WSLAB_ * 2);
  unsigned short* Tb   = (unsigned short*)take((size_t)B_ * 16 * 2048 * 2);
  unsigned short* WT4  = (unsigned short*)take((size_t)4 * H_ * H_ * 2);
  unsigned short* WinT = WT4;
  unsigned short* WqT  = WT4 + (size_t)H_ * H_;
  unsigned short* WvT  = WT4 + (size_t)2 * H_ * H_;
  unsigned short* WoT  = WT4 + (size_t)3 * H_ * H_;
  unsigned short* Wkb  = (unsigned short*)take((size_t)H_ * H_ * 2);
  unsigned short* x_bf   = (unsigned short*)take(BH * 2);
  unsigned short* h_bf   = (unsigned short*)take((size_t)L_ * BH * 2);
  unsigned short* xin_bf = (unsigned short*)take(BH * 2);
  unsigned short* q_bf   = (unsigned short*)take(BH * 2);
  unsigned short* ctx_bf = (unsigned short*)take(BH * 2);
  unsigned short* x2_bf  = (unsigned short*)take(BH * 2);
  unsigned short* rh_bf  = (unsigned short*)take(BH * 2);
  unsigned short* xa     = (unsigned short*)take(BH * 2);
  unsigned short* xb     = (unsigned short*)take(BH * 2);
  float* U   = (float*)take(BH * 4);
  float* Sg  = (float*)take(BH * 4);
  float* Cc  = (float*)take(BH * 4);
  float* XIN = out;   // f32 scratch in d_out[0:B*H]; lnorm overwrites at end

  dim3 blk(256);

  // merged preamble: all conversions + weight transposes in one dispatch
  preamble<<<dim3(19456), blk, 0, stream>>>(
      x, x_bf, hidden, h_bf, Wk, Wkb,
      W_in, Wq, Wv, Wo, WT4,
      Wu, Wr, Wsg, Wc, TW0);

  // 1) xin = x@W_in + b_in + ts_emb[t]
  gemm32<EPI_XIN><<<dim3(512), blk, 0, stream>>>(
      x_bf, WinT, b_in, ts_emb, tsp, nullptr, XIN, xin_bf);
  // 2) q = xin@Wq + bq
  gemm32<EPI_QB><<<dim3(512), blk, 0, stream>>>(
      xin_bf, WqT, bq, nullptr, nullptr, nullptr, nullptr, q_bf);
  // 3) T = per-head Wk^T q
  gemm_t<<<dim3(16, 16, 16), blk, 0, stream>>>(q_bf, Wkb, Tb);
  // 4+5) fused scores/softmax/w (in-place on Tb)
  attn_fused<<<dim3(1024), blk, 0, stream>>>(Tb, hist, Tb);
  // 6) ctx = w @ Wv + bv
  gemm32<EPI_CTX><<<dim3(512), blk, 0, stream>>>(
      Tb, WvT, bv, nullptr, nullptr, nullptr, nullptr, ctx_bf);
  // 7) x2 = xin + ctx@Wo + bo
  gemm32<EPI_X2><<<dim3(512), blk, 0, stream>>>(
      ctx_bf, WoT, bo, nullptr, nullptr, XIN, nullptr, x2_bf);

  // 8) recurrent layers: gates (BM=64 BK=64, 4/CU), cand (BK=64) + next-layer tconv
  unsigned short* xcur = x2_bf;
  for (int i = 0; i < L_; ++i) {
    const float* h_i = hidden + (size_t)i * BH;
    float* nh_f = out + BH + (size_t)i * BH;
    unsigned short* nh_b = (i & 1) ? xb : xa;
    unsigned short* TWcur = (i & 1) ? TW1 : TW0;
    unsigned short* TWnxt = (i < 3) ? ((i & 1) ? TW0 : TW1) : nullptr;
    gemm_gates<<<dim3(1024), blk, 0, stream>>>(
        xcur, h_bf + (size_t)i * BH, TWcur,
        bu + (size_t)i * H_, br + (size_t)i * H_, bs + (size_t)i * H_,
        h_i, U, Sg, rh_bf, Cc);
    int grid = (i < 3) ? 8704 : 512;
    size_t off = (size_t)(i + 1) * WSLAB_;
    cand_tconv<<<dim3(grid), blk, 0, stream>>>(
        rh_bf, TWcur, bc + (size_t)i * H_, Cc, U, Sg, h_i, nh_f, nh_b,
        Wu + off, Wr + off, Wsg + off, Wc + off, TWnxt);
    xcur = nh_b;
  }

  // 9) layernorm of final hidden -> out[0:B*H]
  lnorm<<<dim3(1024), blk, 0, stream>>>(out + BH + (size_t)3 * BH, ln_g, ln_b, out);
}